// Round 4
// baseline (403.335 us; speedup 1.0000x reference)
//
#include <hip/hip_runtime.h>
#include <hip/hip_bf16.h>
#include <math.h>

typedef __bf16 bf16;
typedef __bf16 bf16x8 __attribute__((ext_vector_type(8)));
typedef float floatx4 __attribute__((ext_vector_type(4)));

#define GAS __attribute__((address_space(1)))
#define LAS __attribute__((address_space(3)))

static constexpr int B_ = 16, L_ = 4096, C_ = 512;
static constexpr int M_ = B_ * L_;   // 65536 rows (b,l)
static constexpr int K_ = 3 * C_;    // 1536

// ---- K1: fused prep. blocks [0,16384): cast x f32->bf16; [16384,19456): repack
// w_down; [19456,19520): boundary-row fixup (independent of gemm -> runs hidden
// under the cast grid instead of serializing as its own 64-block launch).
__global__ void prep(const float* __restrict__ x, bf16* __restrict__ xb,
                     const float* __restrict__ wd, bf16* __restrict__ wr,
                     const float* __restrict__ wp, const float* __restrict__ bp,
                     bf16* __restrict__ xp, float* __restrict__ sums) {
    if (blockIdx.x < 16384) {
        const size_t i = ((size_t)blockIdx.x * 256 + threadIdx.x) * 8;
        floatx4 a = *(const floatx4*)(x + i);
        floatx4 b = *(const floatx4*)(x + i + 4);
        bf16x8 o;
#pragma unroll
        for (int j = 0; j < 4; ++j) { o[j] = (bf16)a[j]; o[4 + j] = (bf16)b[j]; }
        *(bf16x8*)(xb + i) = o;
    } else if (blockIdx.x < 19456) {
        int idx = (blockIdx.x - 16384) * 256 + threadIdx.x;   // 512*1536 total
        int o   = idx / K_;
        int rem = idx - o * K_;
        int kk  = rem >> 9;
        int i   = rem & 511;
        wr[idx] = (bf16)wd[o * K_ + i * 3 + kk];
    } else {
        // fixup: rows l in [4092,4096): xp = w_pad . x + b_pad, plus their stats
        const int bid = blockIdx.x - 19456;
        const int b = bid >> 2;
        const int j = bid & 3;
        __shared__ float xrow[C_];
        for (int i = threadIdx.x; i < C_; i += 256)
            xrow[i] = x[(size_t)(b * L_ + j) * C_ + i];
        __syncthreads();
        for (int c = threadIdx.x; c < C_; c += 256) {
            const float* w = wp + (size_t)c * C_;
            float acc = 0.f;
#pragma unroll 4
            for (int i = 0; i < C_; i += 4) {
                floatx4 wv = *(const floatx4*)(w + i);
#pragma unroll
                for (int u = 0; u < 4; ++u) acc += wv[u] * xrow[i + u];
            }
            const float v = acc + bp[c];
            xp[(size_t)(b * L_ + 4092 + j) * C_ + c] = (bf16)v;
            atomicAdd(&sums[c], v);
            atomicAdd(&sums[C_ + c], v * v);
        }
    }
}

// ---- K2: dilated-conv-as-GEMM, 256x256 tile, BK=64, double-buffered LDS.
// Round-3 post-mortem: per-K-tile cycles matched the SERIAL sum of
// LDS-reads(2300) + MFMA(2480) + stage(500) + barriers(800) = 6100 - the
// ds_read->barrier->lgkmcnt->MFMA phases never overlap read and matrix pipes.
// This version software-pipelines ds_reads ONE PHASE AHEAD: phase p's MFMA
// consumes registers read during phase p-1, so the LDS pipe services batch p+1
// while the matrix pipe drains batch p.
// Read rotation (per wave, tile t): R0 = {af<-A.h0, bfr0<-B.h0} issued at
// t-1 ph3 (after vmcnt(8)+barrier guarantees tile t landed); R1 = bfr1<-B.h1
// at ph0; R2 = af<-A.h1 at ph1 (overwrites af after its last use).
// MFMA quadrants: ph0 Q(0,0)=af.h0*bfr0, ph1 Q(0,1)=af.h0*bfr1,
// ph2 Q(1,1)=af.h1*bfr1, ph3 Q(1,0)=af.h1*bfr0 (register-only, no wait).
// Stage slots (tile t+2 into buffer t&1): ph1 A.h0+B.h0, ph2 B.h1, ph3 A.h1.
// WAR safety: every region restage sits >=1 barrier after the lgkmcnt(0) that
// retired its readers (A.h0/B.h0 read-waited ph0 < restage ph1; B.h1 waited
// ph1 < ph2; A.h1 waited ph2 < ph3). vmcnt(8) = 4 oldest units = tile t+1
// fully landed; never drains to 0 until t=22.
__global__ __launch_bounds__(512, 2) void gemm_conv(
    const bf16* __restrict__ x, const bf16* __restrict__ wr,
    const float* __restrict__ bd, bf16* __restrict__ xp, float* __restrict__ sums)
{
    __shared__ bf16 As[2 * 256 * 64];   // 64 KB (2 K-tile buffers, 2 halves each)
    __shared__ bf16 Bs[2 * 256 * 64];   // 64 KB

    const int tid = threadIdx.x;        // 0..511
    const int u   = blockIdx.x;           // 0..511; XCD swizzle pairs n-blocks
    const int mb  = (u & 7) + 8 * (u >> 4);
    const int nb  = (u >> 3) & 1;
    const int m0  = mb * 256;
    const int n0  = nb * 256;

    const int wave = tid >> 6;            // 0..7
    const int lane = tid & 63;
    const int wm = wave & 1;              // 64-row subblock within each 128-half
    const int wn = wave >> 1;             // 32-col subblock within each 128-half
    const int tm = lane & 15;
    const int quad = lane >> 4;

    floatx4 acc[2][4][2][2];
#pragma unroll
    for (int a = 0; a < 2; ++a)
#pragma unroll
        for (int b = 0; b < 4; ++b)
#pragma unroll
            for (int c = 0; c < 2; ++c)
#pragma unroll
                for (int d = 0; d < 2; ++d) acc[a][b][c][d] = floatx4{0.f, 0.f, 0.f, 0.f};

    // staging map: half-tile = 128 rows x 64 cols = 1024 chunks of 16B; 2 sweeps.
    const int r0  = tid >> 3;                       // 0..63  (sweep1 row = r0+64)
    const int c0s = (tid & 7) ^ (r0 & 7);           // XOR source-chunk swizzle

    auto stageA = [&](int t, int eta) {             // 2 global_load_lds (1 unit)
        if (t >= 24) return;
        const int kk = t >> 3, i0 = (t & 7) << 6;
        bf16* dst = As + (t & 1) * 16384 + eta * 8192 + tid * 8;
        int sr0 = m0 + eta * 128 + r0 + 2 * kk;      if (sr0 > M_ - 1) sr0 = M_ - 1;
        int sr1 = m0 + eta * 128 + r0 + 64 + 2 * kk; if (sr1 > M_ - 1) sr1 = M_ - 1;
        __builtin_amdgcn_global_load_lds((const GAS void*)(x + (size_t)sr0 * C_ + i0 + c0s * 8),
                                         (LAS void*)dst, 16, 0, 0);
        __builtin_amdgcn_global_load_lds((const GAS void*)(x + (size_t)sr1 * C_ + i0 + c0s * 8),
                                         (LAS void*)(dst + 4096), 16, 0, 0);
    };
    auto stageB = [&](int t, int eta) {             // 2 global_load_lds (1 unit)
        if (t >= 24) return;
        const int kk = t >> 3, i0 = (t & 7) << 6;
        bf16* dst = Bs + (t & 1) * 16384 + eta * 8192 + tid * 8;
        const bf16* s0 = wr + (size_t)(n0 + eta * 128 + r0) * K_ + kk * C_ + i0 + c0s * 8;
        __builtin_amdgcn_global_load_lds((const GAS void*)s0, (LAS void*)dst, 16, 0, 0);
        __builtin_amdgcn_global_load_lds((const GAS void*)(s0 + (size_t)64 * K_),
                                         (LAS void*)(dst + 4096), 16, 0, 0);
    };

    // read-side swizzled chunk offsets (elems), k-half 0/1
    const int xo0 = (quad ^ (tm & 7)) << 3;
    const int xo1 = ((4 + quad) ^ (tm & 7)) << 3;

    bf16x8 af[4][2];        // A fragments, current half: [mi][kh]
    bf16x8 bfr[2][2][2];    // B fragments, both halves: [nh][ni][kh]

    // prologue: stage tiles 0 and 1 fully (8 units); vmcnt(8)=4 units left ->
    // tile 0 landed; barrier publishes; issue R0(0).
    stageA(0, 0); stageB(0, 0); stageB(0, 1); stageA(0, 1);
    stageA(1, 0); stageB(1, 0); stageB(1, 1); stageA(1, 1);
    asm volatile("s_waitcnt vmcnt(8)" ::: "memory");
    asm volatile("s_barrier" ::: "memory");
#pragma unroll
    for (int mi = 0; mi < 4; ++mi) {
        const bf16* p = As + (wm * 64 + mi * 16 + tm) * 64;
        af[mi][0] = *(const bf16x8*)(p + xo0);
        af[mi][1] = *(const bf16x8*)(p + xo1);
    }
#pragma unroll
    for (int ni = 0; ni < 2; ++ni) {
        const bf16* p = Bs + (wn * 32 + ni * 16 + tm) * 64;
        bfr[0][ni][0] = *(const bf16x8*)(p + xo0);
        bfr[0][ni][1] = *(const bf16x8*)(p + xo1);
    }

#pragma unroll 2
    for (int t = 0; t < 24; ++t) {
        const bf16* Ab  = As + (t & 1) * 16384;
        const bf16* Bb  = Bs + (t & 1) * 16384;
        const bf16* AbN = As + ((t + 1) & 1) * 16384;
        const bf16* BbN = Bs + ((t + 1) & 1) * 16384;

        // ---- ph0: wait R0; MFMA Q(0,0); issue R1 (bfr1 <- B.h1)
        asm volatile("s_waitcnt lgkmcnt(0)" ::: "memory");
        __builtin_amdgcn_sched_barrier(0);
        __builtin_amdgcn_s_setprio(1);
#pragma unroll
        for (int kh = 0; kh < 2; ++kh)
#pragma unroll
            for (int mi = 0; mi < 4; ++mi)
#pragma unroll
                for (int ni = 0; ni < 2; ++ni)
                    acc[0][mi][0][ni] = __builtin_amdgcn_mfma_f32_16x16x32_bf16(
                        af[mi][kh], bfr[0][ni][kh], acc[0][mi][0][ni], 0, 0, 0);
        __builtin_amdgcn_s_setprio(0);
        __builtin_amdgcn_sched_barrier(0);
#pragma unroll
        for (int ni = 0; ni < 2; ++ni) {
            const bf16* p = Bb + (128 + wn * 32 + ni * 16 + tm) * 64;
            bfr[1][ni][0] = *(const bf16x8*)(p + xo0);
            bfr[1][ni][1] = *(const bf16x8*)(p + xo1);
        }
        asm volatile("s_barrier" ::: "memory");

        // ---- ph1: wait R1; MFMA Q(0,1); issue R2 (af <- A.h1, overwrite);
        //           stage (t+2).A.h0 + (t+2).B.h0
        asm volatile("s_waitcnt lgkmcnt(0)" ::: "memory");
        __builtin_amdgcn_sched_barrier(0);
        __builtin_amdgcn_s_setprio(1);
#pragma unroll
        for (int kh = 0; kh < 2; ++kh)
#pragma unroll
            for (int mi = 0; mi < 4; ++mi)
#pragma unroll
                for (int ni = 0; ni < 2; ++ni)
                    acc[0][mi][1][ni] = __builtin_amdgcn_mfma_f32_16x16x32_bf16(
                        af[mi][kh], bfr[1][ni][kh], acc[0][mi][1][ni], 0, 0, 0);
        __builtin_amdgcn_s_setprio(0);
        __builtin_amdgcn_sched_barrier(0);          // pin: af.h0 consumed before overwrite
#pragma unroll
        for (int mi = 0; mi < 4; ++mi) {
            const bf16* p = Ab + (128 + wm * 64 + mi * 16 + tm) * 64;
            af[mi][0] = *(const bf16x8*)(p + xo0);
            af[mi][1] = *(const bf16x8*)(p + xo1);
        }
        stageA(t + 2, 0);
        stageB(t + 2, 0);
        asm volatile("s_barrier" ::: "memory");

        // ---- ph2: wait R2; MFMA Q(1,1); stage (t+2).B.h1
        asm volatile("s_waitcnt lgkmcnt(0)" ::: "memory");
        __builtin_amdgcn_sched_barrier(0);
        __builtin_amdgcn_s_setprio(1);
#pragma unroll
        for (int kh = 0; kh < 2; ++kh)
#pragma unroll
            for (int mi = 0; mi < 4; ++mi)
#pragma unroll
                for (int ni = 0; ni < 2; ++ni)
                    acc[1][mi][1][ni] = __builtin_amdgcn_mfma_f32_16x16x32_bf16(
                        af[mi][kh], bfr[1][ni][kh], acc[1][mi][1][ni], 0, 0, 0);
        __builtin_amdgcn_s_setprio(0);
        stageB(t + 2, 1);
        asm volatile("s_barrier" ::: "memory");

        // ---- ph3: stage (t+2).A.h1; counted vmcnt (tile t+1 landed); barrier;
        //           MFMA Q(1,0) (register-only, no wait); issue R0(t+1)
        stageA(t + 2, 1);
        if (t < 22)       { asm volatile("s_waitcnt vmcnt(8)" ::: "memory"); }
        else if (t == 22) { asm volatile("s_waitcnt vmcnt(0)" ::: "memory"); }
        asm volatile("s_barrier" ::: "memory");
        __builtin_amdgcn_s_setprio(1);
#pragma unroll
        for (int kh = 0; kh < 2; ++kh)
#pragma unroll
            for (int mi = 0; mi < 4; ++mi)
#pragma unroll
                for (int ni = 0; ni < 2; ++ni)
                    acc[1][mi][0][ni] = __builtin_amdgcn_mfma_f32_16x16x32_bf16(
                        af[mi][kh], bfr[0][ni][kh], acc[1][mi][0][ni], 0, 0, 0);
        __builtin_amdgcn_s_setprio(0);
        __builtin_amdgcn_sched_barrier(0);          // pin: af.h1/bfr0 consumed first
        if (t < 23) {
#pragma unroll
            for (int mi = 0; mi < 4; ++mi) {
                const bf16* p = AbN + (wm * 64 + mi * 16 + tm) * 64;
                af[mi][0] = *(const bf16x8*)(p + xo0);
                af[mi][1] = *(const bf16x8*)(p + xo1);
            }
#pragma unroll
            for (int ni = 0; ni < 2; ++ni) {
                const bf16* p = BbN + (wn * 32 + ni * 16 + tm) * 64;
                bfr[0][ni][0] = *(const bf16x8*)(p + xo0);
                bfr[0][ni][1] = *(const bf16x8*)(p + xo1);
            }
        }
        asm volatile("s_barrier" ::: "memory");
    }

    // epilogue: + bias, store bf16 (valid rows only; boundary rows owned by the
    // fixup branch of prep), fused stats. C/D: col=lane&15, row=quad*4+reg.
    float bias[2][2], s[2][2], q[2][2];
#pragma unroll
    for (int nh = 0; nh < 2; ++nh)
#pragma unroll
        for (int ni = 0; ni < 2; ++ni) {
            bias[nh][ni] = bd[n0 + nh * 128 + wn * 32 + ni * 16 + tm];
            s[nh][ni] = 0.f; q[nh][ni] = 0.f;
        }

#pragma unroll
    for (int mh = 0; mh < 2; ++mh)
#pragma unroll
        for (int mi = 0; mi < 4; ++mi)
#pragma unroll
            for (int r = 0; r < 4; ++r) {
                const int m = m0 + mh * 128 + wm * 64 + mi * 16 + quad * 4 + r;
                const bool valid = (m & (L_ - 1)) < L_ - 4;
                bf16* dst = xp + (size_t)m * C_ + n0 + wn * 32 + tm;
#pragma unroll
                for (int nh = 0; nh < 2; ++nh)
#pragma unroll
                    for (int ni = 0; ni < 2; ++ni) {
                        const float v = acc[mh][mi][nh][ni][r] + bias[nh][ni];
                        if (valid) {
                            dst[nh * 128 + ni * 16] = (bf16)v;
                            s[nh][ni] += v; q[nh][ni] += v * v;
                        }
                    }
            }
#pragma unroll
    for (int nh = 0; nh < 2; ++nh)
#pragma unroll
        for (int ni = 0; ni < 2; ++ni) {
            float sv = s[nh][ni], qv = q[nh][ni];
            sv += __shfl_xor(sv, 16); sv += __shfl_xor(sv, 32);
            qv += __shfl_xor(qv, 16); qv += __shfl_xor(qv, 32);
            if (quad == 0) {
                const int c = n0 + nh * 128 + wn * 32 + ni * 16 + tm;
                atomicAdd(&sums[c], sv);
                atomicAdd(&sums[C_ + c], qv);
            }
        }
}

// ---- K4: BN(from raw sums) -> ELU -> +residual(bf16) -> maxpool(3,2,pad1) -> [B,L/2,C] f32
__global__ void final_pool(const bf16* __restrict__ xp, const bf16* __restrict__ xb,
                           const float* __restrict__ sums, const float* __restrict__ gamma,
                           const float* __restrict__ beta, float* __restrict__ out)
{
    const int gid = blockIdx.x * 256 + threadIdx.x;  // B * 2048 * 64 groups of 8 ch
    const int cg = gid & 63;
    const int t  = (gid >> 6) & 2047;
    const int b  = gid >> 17;
    const int c0 = cg << 3;

    float sc[8], sh[8];
    const float invn = 1.0f / 65536.0f;
#pragma unroll
    for (int j = 0; j < 8; ++j) {
        const int c = c0 + j;
        float mean = sums[c] * invn;
        float var  = sums[C_ + c] * invn - mean * mean;
        float scale = gamma[c] * rsqrtf(var + 1e-5f);
        sc[j] = scale;
        sh[j] = beta[c] - mean * scale;
    }

    float best[8];
#pragma unroll
    for (int j = 0; j < 8; ++j) best[j] = -INFINITY;

#pragma unroll
    for (int dl = -1; dl <= 1; ++dl) {
        const int l = 2 * t + dl;
        if (l < 0) continue;                        // right edge never exceeds 4095
        const size_t off = (size_t)(b * L_ + l) * C_ + c0;
        bf16x8 xpv = *(const bf16x8*)(xp + off);
        bf16x8 xv  = *(const bf16x8*)(xb + off);
#pragma unroll
        for (int j = 0; j < 8; ++j) {
            float z = sc[j] * (float)xpv[j] + sh[j];
            float y = (z > 0.f) ? z : (__expf(z) - 1.f);
            y += (float)xv[j];
            best[j] = fmaxf(best[j], y);
        }
    }
    floatx4 o0, o1;
#pragma unroll
    for (int j = 0; j < 4; ++j) { o0[j] = best[j]; o1[j] = best[4 + j]; }
    *(floatx4*)(out + (size_t)gid * 8) = o0;
    *(floatx4*)(out + (size_t)gid * 8 + 4) = o1;
}

extern "C" void kernel_launch(void* const* d_in, const int* in_sizes, int n_in,
                              void* d_out, int out_size, void* d_ws, size_t ws_size,
                              hipStream_t stream)
{
    const float* x      = (const float*)d_in[0];
    const float* w_down = (const float*)d_in[1];
    const float* b_down = (const float*)d_in[2];
    const float* w_pad  = (const float*)d_in[3];
    const float* b_pad  = (const float*)d_in[4];
    const float* gamma  = (const float*)d_in[5];
    const float* beta   = (const float*)d_in[6];
    float* out = (float*)d_out;

    char* ws = (char*)d_ws;
    bf16*  xb   = (bf16*)ws;                                        // 64 MiB  [B*L][C] bf16 copy of x
    bf16*  xp   = (bf16*)(ws + (size_t)M_ * C_ * 2);                // 64 MiB  [B*L][C]
    bf16*  wr   = (bf16*)(ws + (size_t)M_ * C_ * 4);                // 1.5 MiB [O][K]
    float* sums = (float*)(ws + (size_t)M_ * C_ * 4 + (size_t)C_ * K_ * 2);  // 1024 f32

    hipMemsetAsync(sums, 0, 2 * C_ * sizeof(float), stream);
    prep<<<dim3(16384 + 3072 + 64), dim3(256), 0, stream>>>(x, xb, w_down, wr,
                                                            w_pad, b_pad, xp, sums);
    gemm_conv<<<dim3(512), dim3(512), 0, stream>>>(xb, wr, b_down, xp, sums);
    final_pool<<<dim3(8192), dim3(256), 0, stream>>>(xp, xb, sums, gamma, beta, out);
}

// Round 5
// 402.250 us; speedup vs baseline: 1.0027x; 1.0027x over previous
//
#include <hip/hip_runtime.h>
#include <hip/hip_bf16.h>
#include <math.h>

typedef __bf16 bf16;
typedef __bf16 bf16x8 __attribute__((ext_vector_type(8)));
typedef float floatx4 __attribute__((ext_vector_type(4)));

#define GAS __attribute__((address_space(1)))
#define LAS __attribute__((address_space(3)))

static constexpr int B_ = 16, L_ = 4096, C_ = 512;
static constexpr int M_ = B_ * L_;   // 65536 rows (b,l)
static constexpr int K_ = 3 * C_;    // 1536

// ---- K1: fused prep, grid-strided (Guideline 11). Round-4 post-mortem: 19520
// tiny blocks ran at 1.25 TB/s / VALUBusy 1.9% -- per-block launch churn, not
// BW. 2048 fat blocks stride the 19456 cast/repack units; 64 blocks do fixup.
__global__ void prep(const float* __restrict__ x, bf16* __restrict__ xb,
                     const float* __restrict__ wd, bf16* __restrict__ wr,
                     const float* __restrict__ wp, const float* __restrict__ bp,
                     bf16* __restrict__ xp, float* __restrict__ sums) {
    __shared__ float xrow[C_];
    if (blockIdx.x < 2048) {
        for (int u = blockIdx.x; u < 19456; u += 2048) {
            if (u < 16384) {
                const size_t i = ((size_t)u * 256 + threadIdx.x) * 8;
                floatx4 a = *(const floatx4*)(x + i);
                floatx4 b = *(const floatx4*)(x + i + 4);
                bf16x8 o;
#pragma unroll
                for (int j = 0; j < 4; ++j) { o[j] = (bf16)a[j]; o[4 + j] = (bf16)b[j]; }
                *(bf16x8*)(xb + i) = o;
            } else {
                int idx = (u - 16384) * 256 + threadIdx.x;   // 512*1536 total
                int o   = idx / K_;
                int rem = idx - o * K_;
                int kk  = rem >> 9;
                int i   = rem & 511;
                wr[idx] = (bf16)wd[o * K_ + i * 3 + kk];
            }
        }
    } else {
        // fixup: rows l in [4092,4096): xp = w_pad . x + b_pad, plus their stats
        const int bid = blockIdx.x - 2048;
        const int b = bid >> 2;
        const int j = bid & 3;
        for (int i = threadIdx.x; i < C_; i += 256)
            xrow[i] = x[(size_t)(b * L_ + j) * C_ + i];
        __syncthreads();
        for (int c = threadIdx.x; c < C_; c += 256) {
            const float* w = wp + (size_t)c * C_;
            float acc = 0.f;
#pragma unroll 4
            for (int i = 0; i < C_; i += 4) {
                floatx4 wv = *(const floatx4*)(w + i);
#pragma unroll
                for (int u = 0; u < 4; ++u) acc += wv[u] * xrow[i + u];
            }
            const float v = acc + bp[c];
            xp[(size_t)(b * L_ + 4092 + j) * C_ + c] = (bf16)v;
            atomicAdd(&sums[c], v);
            atomicAdd(&sums[C_ + c], v * v);
        }
    }
}

// ---- K2: dilated-conv-as-GEMM, 256x256 tile, BK=64, double-buffered LDS,
// ds_reads pipelined one phase ahead, counted vmcnt, setprio, XOR swizzle.
// Round-4 tweak: removed the post-MFMA sched_barrier(0) walls (register WAR is
// compiler-enforced; the walls pinned order and blocked ds_read/MFMA
// co-scheduling -- the m141 trap). Rule-#18 fences after lgkmcnt(0) kept.
// Read rotation (per wave, tile t): R0 = {af<-A.h0, bfr0<-B.h0} issued at
// t-1 ph3; R1 = bfr1<-B.h1 at ph0; R2 = af<-A.h1 at ph1.
// MFMA quadrants: ph0 Q(0,0), ph1 Q(0,1), ph2 Q(1,1), ph3 Q(1,0).
// Stage slots (tile t+2 into buffer t&1): ph1 A.h0+B.h0, ph2 B.h1, ph3 A.h1.
// WAR safety: every restage sits >=1 barrier after the lgkmcnt(0) that retired
// its readers. vmcnt(8) = tile t+1 fully landed; drains to 0 only at t=22.
__global__ __launch_bounds__(512, 2) void gemm_conv(
    const bf16* __restrict__ x, const bf16* __restrict__ wr,
    const float* __restrict__ bd, bf16* __restrict__ xp, float* __restrict__ sums)
{
    __shared__ bf16 As[2 * 256 * 64];   // 64 KB (2 K-tile buffers, 2 halves each)
    __shared__ bf16 Bs[2 * 256 * 64];   // 64 KB

    const int tid = threadIdx.x;        // 0..511
    const int u   = blockIdx.x;           // 0..511; XCD swizzle pairs n-blocks
    const int mb  = (u & 7) + 8 * (u >> 4);
    const int nb  = (u >> 3) & 1;
    const int m0  = mb * 256;
    const int n0  = nb * 256;

    const int wave = tid >> 6;            // 0..7
    const int lane = tid & 63;
    const int wm = wave & 1;              // 64-row subblock within each 128-half
    const int wn = wave >> 1;             // 32-col subblock within each 128-half
    const int tm = lane & 15;
    const int quad = lane >> 4;

    floatx4 acc[2][4][2][2];
#pragma unroll
    for (int a = 0; a < 2; ++a)
#pragma unroll
        for (int b = 0; b < 4; ++b)
#pragma unroll
            for (int c = 0; c < 2; ++c)
#pragma unroll
                for (int d = 0; d < 2; ++d) acc[a][b][c][d] = floatx4{0.f, 0.f, 0.f, 0.f};

    // staging map: half-tile = 128 rows x 64 cols = 1024 chunks of 16B; 2 sweeps.
    const int r0  = tid >> 3;                       // 0..63  (sweep1 row = r0+64)
    const int c0s = (tid & 7) ^ (r0 & 7);           // XOR source-chunk swizzle

    auto stageA = [&](int t, int eta) {             // 2 global_load_lds (1 unit)
        if (t >= 24) return;
        const int kk = t >> 3, i0 = (t & 7) << 6;
        bf16* dst = As + (t & 1) * 16384 + eta * 8192 + tid * 8;
        int sr0 = m0 + eta * 128 + r0 + 2 * kk;      if (sr0 > M_ - 1) sr0 = M_ - 1;
        int sr1 = m0 + eta * 128 + r0 + 64 + 2 * kk; if (sr1 > M_ - 1) sr1 = M_ - 1;
        __builtin_amdgcn_global_load_lds((const GAS void*)(x + (size_t)sr0 * C_ + i0 + c0s * 8),
                                         (LAS void*)dst, 16, 0, 0);
        __builtin_amdgcn_global_load_lds((const GAS void*)(x + (size_t)sr1 * C_ + i0 + c0s * 8),
                                         (LAS void*)(dst + 4096), 16, 0, 0);
    };
    auto stageB = [&](int t, int eta) {             // 2 global_load_lds (1 unit)
        if (t >= 24) return;
        const int kk = t >> 3, i0 = (t & 7) << 6;
        bf16* dst = Bs + (t & 1) * 16384 + eta * 8192 + tid * 8;
        const bf16* s0 = wr + (size_t)(n0 + eta * 128 + r0) * K_ + kk * C_ + i0 + c0s * 8;
        __builtin_amdgcn_global_load_lds((const GAS void*)s0, (LAS void*)dst, 16, 0, 0);
        __builtin_amdgcn_global_load_lds((const GAS void*)(s0 + (size_t)64 * K_),
                                         (LAS void*)(dst + 4096), 16, 0, 0);
    };

    // read-side swizzled chunk offsets (elems), k-half 0/1
    const int xo0 = (quad ^ (tm & 7)) << 3;
    const int xo1 = ((4 + quad) ^ (tm & 7)) << 3;

    bf16x8 af[4][2];        // A fragments, current half: [mi][kh]
    bf16x8 bfr[2][2][2];    // B fragments, both halves: [nh][ni][kh]

    // prologue: stage tiles 0 and 1 fully (8 units); vmcnt(8)=4 units left ->
    // tile 0 landed; barrier publishes; issue R0(0).
    stageA(0, 0); stageB(0, 0); stageB(0, 1); stageA(0, 1);
    stageA(1, 0); stageB(1, 0); stageB(1, 1); stageA(1, 1);
    asm volatile("s_waitcnt vmcnt(8)" ::: "memory");
    asm volatile("s_barrier" ::: "memory");
#pragma unroll
    for (int mi = 0; mi < 4; ++mi) {
        const bf16* p = As + (wm * 64 + mi * 16 + tm) * 64;
        af[mi][0] = *(const bf16x8*)(p + xo0);
        af[mi][1] = *(const bf16x8*)(p + xo1);
    }
#pragma unroll
    for (int ni = 0; ni < 2; ++ni) {
        const bf16* p = Bs + (wn * 32 + ni * 16 + tm) * 64;
        bfr[0][ni][0] = *(const bf16x8*)(p + xo0);
        bfr[0][ni][1] = *(const bf16x8*)(p + xo1);
    }

#pragma unroll 2
    for (int t = 0; t < 24; ++t) {
        const bf16* Ab  = As + (t & 1) * 16384;
        const bf16* Bb  = Bs + (t & 1) * 16384;
        const bf16* AbN = As + ((t + 1) & 1) * 16384;
        const bf16* BbN = Bs + ((t + 1) & 1) * 16384;

        // ---- ph0: wait R0; MFMA Q(0,0); issue R1 (bfr1 <- B.h1)
        asm volatile("s_waitcnt lgkmcnt(0)" ::: "memory");
        __builtin_amdgcn_sched_barrier(0);
        __builtin_amdgcn_s_setprio(1);
#pragma unroll
        for (int kh = 0; kh < 2; ++kh)
#pragma unroll
            for (int mi = 0; mi < 4; ++mi)
#pragma unroll
                for (int ni = 0; ni < 2; ++ni)
                    acc[0][mi][0][ni] = __builtin_amdgcn_mfma_f32_16x16x32_bf16(
                        af[mi][kh], bfr[0][ni][kh], acc[0][mi][0][ni], 0, 0, 0);
        __builtin_amdgcn_s_setprio(0);
#pragma unroll
        for (int ni = 0; ni < 2; ++ni) {
            const bf16* p = Bb + (128 + wn * 32 + ni * 16 + tm) * 64;
            bfr[1][ni][0] = *(const bf16x8*)(p + xo0);
            bfr[1][ni][1] = *(const bf16x8*)(p + xo1);
        }
        asm volatile("s_barrier" ::: "memory");

        // ---- ph1: wait R1; MFMA Q(0,1); issue R2 (af <- A.h1, overwrite);
        //           stage (t+2).A.h0 + (t+2).B.h0
        asm volatile("s_waitcnt lgkmcnt(0)" ::: "memory");
        __builtin_amdgcn_sched_barrier(0);
        __builtin_amdgcn_s_setprio(1);
#pragma unroll
        for (int kh = 0; kh < 2; ++kh)
#pragma unroll
            for (int mi = 0; mi < 4; ++mi)
#pragma unroll
                for (int ni = 0; ni < 2; ++ni)
                    acc[0][mi][1][ni] = __builtin_amdgcn_mfma_f32_16x16x32_bf16(
                        af[mi][kh], bfr[1][ni][kh], acc[0][mi][1][ni], 0, 0, 0);
        __builtin_amdgcn_s_setprio(0);
#pragma unroll
        for (int mi = 0; mi < 4; ++mi) {
            const bf16* p = Ab + (128 + wm * 64 + mi * 16 + tm) * 64;
            af[mi][0] = *(const bf16x8*)(p + xo0);
            af[mi][1] = *(const bf16x8*)(p + xo1);
        }
        stageA(t + 2, 0);
        stageB(t + 2, 0);
        asm volatile("s_barrier" ::: "memory");

        // ---- ph2: wait R2; MFMA Q(1,1); stage (t+2).B.h1
        asm volatile("s_waitcnt lgkmcnt(0)" ::: "memory");
        __builtin_amdgcn_sched_barrier(0);
        __builtin_amdgcn_s_setprio(1);
#pragma unroll
        for (int kh = 0; kh < 2; ++kh)
#pragma unroll
            for (int mi = 0; mi < 4; ++mi)
#pragma unroll
                for (int ni = 0; ni < 2; ++ni)
                    acc[1][mi][1][ni] = __builtin_amdgcn_mfma_f32_16x16x32_bf16(
                        af[mi][kh], bfr[1][ni][kh], acc[1][mi][1][ni], 0, 0, 0);
        __builtin_amdgcn_s_setprio(0);
        stageB(t + 2, 1);
        asm volatile("s_barrier" ::: "memory");

        // ---- ph3: stage (t+2).A.h1; counted vmcnt (tile t+1 landed); barrier;
        //           MFMA Q(1,0) (register-only, no wait); issue R0(t+1)
        stageA(t + 2, 1);
        if (t < 22)       { asm volatile("s_waitcnt vmcnt(8)" ::: "memory"); }
        else if (t == 22) { asm volatile("s_waitcnt vmcnt(0)" ::: "memory"); }
        asm volatile("s_barrier" ::: "memory");
        __builtin_amdgcn_s_setprio(1);
#pragma unroll
        for (int kh = 0; kh < 2; ++kh)
#pragma unroll
            for (int mi = 0; mi < 4; ++mi)
#pragma unroll
                for (int ni = 0; ni < 2; ++ni)
                    acc[1][mi][0][ni] = __builtin_amdgcn_mfma_f32_16x16x32_bf16(
                        af[mi][kh], bfr[0][ni][kh], acc[1][mi][0][ni], 0, 0, 0);
        __builtin_amdgcn_s_setprio(0);
        if (t < 23) {
#pragma unroll
            for (int mi = 0; mi < 4; ++mi) {
                const bf16* p = AbN + (wm * 64 + mi * 16 + tm) * 64;
                af[mi][0] = *(const bf16x8*)(p + xo0);
                af[mi][1] = *(const bf16x8*)(p + xo1);
            }
#pragma unroll
            for (int ni = 0; ni < 2; ++ni) {
                const bf16* p = BbN + (wn * 32 + ni * 16 + tm) * 64;
                bfr[0][ni][0] = *(const bf16x8*)(p + xo0);
                bfr[0][ni][1] = *(const bf16x8*)(p + xo1);
            }
        }
        asm volatile("s_barrier" ::: "memory");
    }

    // epilogue: + bias, store bf16 (valid rows only; boundary rows owned by the
    // fixup branch of prep), fused stats. C/D: col=lane&15, row=quad*4+reg.
    float bias[2][2], s[2][2], q[2][2];
#pragma unroll
    for (int nh = 0; nh < 2; ++nh)
#pragma unroll
        for (int ni = 0; ni < 2; ++ni) {
            bias[nh][ni] = bd[n0 + nh * 128 + wn * 32 + ni * 16 + tm];
            s[nh][ni] = 0.f; q[nh][ni] = 0.f;
        }

#pragma unroll
    for (int mh = 0; mh < 2; ++mh)
#pragma unroll
        for (int mi = 0; mi < 4; ++mi)
#pragma unroll
            for (int r = 0; r < 4; ++r) {
                const int m = m0 + mh * 128 + wm * 64 + mi * 16 + quad * 4 + r;
                const bool valid = (m & (L_ - 1)) < L_ - 4;
                bf16* dst = xp + (size_t)m * C_ + n0 + wn * 32 + tm;
#pragma unroll
                for (int nh = 0; nh < 2; ++nh)
#pragma unroll
                    for (int ni = 0; ni < 2; ++ni) {
                        const float v = acc[mh][mi][nh][ni][r] + bias[nh][ni];
                        if (valid) {
                            dst[nh * 128 + ni * 16] = (bf16)v;
                            s[nh][ni] += v; q[nh][ni] += v * v;
                        }
                    }
            }
#pragma unroll
    for (int nh = 0; nh < 2; ++nh)
#pragma unroll
        for (int ni = 0; ni < 2; ++ni) {
            float sv = s[nh][ni], qv = q[nh][ni];
            sv += __shfl_xor(sv, 16); sv += __shfl_xor(sv, 32);
            qv += __shfl_xor(qv, 16); qv += __shfl_xor(qv, 32);
            if (quad == 0) {
                const int c = n0 + nh * 128 + wn * 32 + ni * 16 + tm;
                atomicAdd(&sums[c], sv);
                atomicAdd(&sums[C_ + c], qv);
            }
        }
}

// ---- K4: BN(from raw sums) -> ELU -> +residual(bf16) -> maxpool(3,2,pad1) ->
// [B,L/2,C] f32. Grid-strided to 2048 blocks (G11); each thread keeps a fixed
// (channel-group, t) so BN coefficients hoist, and strides over b.
__global__ void final_pool(const bf16* __restrict__ xp, const bf16* __restrict__ xb,
                           const float* __restrict__ sums, const float* __restrict__ gamma,
                           const float* __restrict__ beta, float* __restrict__ out)
{
    const int gid0 = blockIdx.x * 256 + threadIdx.x;  // 524288 ids; total 2097152
    const int cg = gid0 & 63;
    const int t  = (gid0 >> 6) & 2047;
    const int b0 = gid0 >> 17;                        // 0..3
    const int c0 = cg << 3;

    float sc[8], sh[8];
    const float invn = 1.0f / 65536.0f;
#pragma unroll
    for (int j = 0; j < 8; ++j) {
        const int c = c0 + j;
        float mean = sums[c] * invn;
        float var  = sums[C_ + c] * invn - mean * mean;
        float scale = gamma[c] * rsqrtf(var + 1e-5f);
        sc[j] = scale;
        sh[j] = beta[c] - mean * scale;
    }

    for (int b = b0; b < B_; b += 4) {
        float best[8];
#pragma unroll
        for (int j = 0; j < 8; ++j) best[j] = -INFINITY;

#pragma unroll
        for (int dl = -1; dl <= 1; ++dl) {
            const int l = 2 * t + dl;
            if (l < 0) continue;                        // right edge never exceeds 4095
            const size_t off = (size_t)(b * L_ + l) * C_ + c0;
            bf16x8 xpv = *(const bf16x8*)(xp + off);
            bf16x8 xv  = *(const bf16x8*)(xb + off);
#pragma unroll
            for (int j = 0; j < 8; ++j) {
                float z = sc[j] * (float)xpv[j] + sh[j];
                float y = (z > 0.f) ? z : (__expf(z) - 1.f);
                y += (float)xv[j];
                best[j] = fmaxf(best[j], y);
            }
        }
        floatx4 o0, o1;
#pragma unroll
        for (int j = 0; j < 4; ++j) { o0[j] = best[j]; o1[j] = best[4 + j]; }
        const size_t og = ((size_t)b << 17) | ((size_t)t << 6) | cg;
        *(floatx4*)(out + og * 8) = o0;
        *(floatx4*)(out + og * 8 + 4) = o1;
    }
}

extern "C" void kernel_launch(void* const* d_in, const int* in_sizes, int n_in,
                              void* d_out, int out_size, void* d_ws, size_t ws_size,
                              hipStream_t stream)
{
    const float* x      = (const float*)d_in[0];
    const float* w_down = (const float*)d_in[1];
    const float* b_down = (const float*)d_in[2];
    const float* w_pad  = (const float*)d_in[3];
    const float* b_pad  = (const float*)d_in[4];
    const float* gamma  = (const float*)d_in[5];
    const float* beta   = (const float*)d_in[6];
    float* out = (float*)d_out;

    char* ws = (char*)d_ws;
    bf16*  xb   = (bf16*)ws;                                        // 64 MiB  [B*L][C] bf16 copy of x
    bf16*  xp   = (bf16*)(ws + (size_t)M_ * C_ * 2);                // 64 MiB  [B*L][C]
    bf16*  wr   = (bf16*)(ws + (size_t)M_ * C_ * 4);                // 1.5 MiB [O][K]
    float* sums = (float*)(ws + (size_t)M_ * C_ * 4 + (size_t)C_ * K_ * 2);  // 1024 f32

    hipMemsetAsync(sums, 0, 2 * C_ * sizeof(float), stream);
    prep<<<dim3(2048 + 64), dim3(256), 0, stream>>>(x, xb, w_down, wr,
                                                    w_pad, b_pad, xp, sums);
    gemm_conv<<<dim3(512), dim3(512), 0, stream>>>(xb, wr, b_down, xp, sums);
    final_pool<<<dim3(2048), dim3(256), 0, stream>>>(xp, xb, sums, gamma, beta, out);
}